// Round 1
// baseline (302.600 us; speedup 1.0000x reference)
//
#include <hip/hip_runtime.h>

#define NTOK 49
#define NH 6
#define HD 32
#define DIM 192
#define QKV_DIM 576
#define PI_F 3.14159265358979323846f

typedef __bf16 bf16_t;
typedef __bf16 bf16x4 __attribute__((ext_vector_type(4)));
typedef __bf16 bf16x8 __attribute__((ext_vector_type(8)));
typedef float f32x4 __attribute__((ext_vector_type(4)));

// ---------------- Kernel 0: convert weights fp32 -> bf16 ----------------
__global__ __launch_bounds__(256) void cvt_weights(const float* __restrict__ qkv_w,
                                                   const float* __restrict__ proj_w,
                                                   bf16_t* __restrict__ wq,
                                                   bf16_t* __restrict__ wp) {
    int idx = blockIdx.x * 256 + threadIdx.x;
    if (idx < QKV_DIM * DIM) {
        wq[idx] = (bf16_t)qkv_w[idx];
    } else {
        int j = idx - QKV_DIM * DIM;
        if (j < DIM * DIM) wp[j] = (bf16_t)proj_w[j];
    }
}

// pack 4 floats into bf16x4 viewed as int2 (regs r0..r3)
__device__ __forceinline__ int2 pack4(float a, float b, float c, float d) {
    bf16x4 t = { (bf16_t)a, (bf16_t)b, (bf16_t)c, (bf16_t)d };
    union { bf16x4 v; int2 i; } u;
    u.v = t;
    return u.i;
}

// Cross-quad fragment assembly.
// Source: packed tiles p0 (ct/nt = base) and p1 (base+1); lane (qs,l16) reg r
//   holds elem [idx = qs*4+r] of its tile at token/col l16.
// Target: lane (q,l16) element e (0..7) = tile (q>>1), idx = (q&1)*8 + e.
//   -> low half from src lane 2(q&1)*16+l16, high half from +16, tile by q>>1.
__device__ __forceinline__ bf16x8 asm_frag(int2 p0, int2 p1, int src_lo, bool sel_hi) {
    int a0x = __shfl(p0.x, src_lo),      a0y = __shfl(p0.y, src_lo);
    int a1x = __shfl(p0.x, src_lo + 16), a1y = __shfl(p0.y, src_lo + 16);
    int b0x = __shfl(p1.x, src_lo),      b0y = __shfl(p1.y, src_lo);
    int b1x = __shfl(p1.x, src_lo + 16), b1y = __shfl(p1.y, src_lo + 16);
    union { int x[4]; bf16x8 v; } u;
    u.x[0] = sel_hi ? b0x : a0x;
    u.x[1] = sel_hi ? b0y : a0y;
    u.x[2] = sel_hi ? b1x : a1x;
    u.x[3] = sel_hi ? b1y : a1y;
    return u.v;
}

// ---------------- Kernel 1: fully-fused window attention ----------------
// One block (384 thr = 6 waves) per window; wave w = head w.
// LDS cut 129.5KB -> ~50KB so 2 blocks/CU are resident (__launch_bounds__(384,3)
// caps VGPR at 170 => 12 waves/CU).
// Q, K and P never touch LDS: swapped-operand MFMA puts lane l16 = token on the
// gemm outputs, and a fixed cross-quad ds_bpermute repack (asm_frag) builds the
// attention fragments in registers. Softmax rows are lane-local (2 shuffles).
__global__ __launch_bounds__(384, 3) void fused_win_attn(
        const float* __restrict__ x,
        const float* __restrict__ Dp,
        const bf16_t* __restrict__ wq,
        const float* __restrict__ qkv_b,
        const bf16_t* __restrict__ wp,
        const float* __restrict__ proj_b,
        const float* __restrict__ a_p,
        const float* __restrict__ b_p,
        const float* __restrict__ a_r,
        const float* __restrict__ b_r,
        float* __restrict__ out) {
    __shared__ __align__(16) bf16_t sh_xo[49 * 200];      // x, later O (19.6 KB)
    __shared__ __align__(16) bf16_t vt_sh[NH][32 * 72];   // per-wave v^T [d][token] (27.6 KB)
    __shared__ float bias_sh[NH][169];                    // (4.1 KB)

    const int tid  = threadIdx.x;
    const int w    = tid >> 6;        // wave id == head id
    const int lane = tid & 63;
    const int l16  = lane & 15;
    const int quad = lane >> 4;
    const int win  = blockIdx.x;

    bf16_t* vt     = vt_sh[w];
    float*  bias13 = bias_sh[w];

    // ---- Phase 0: stage x (49x192 fp32 -> bf16 LDS) ----
    const float* xg = x + (size_t)win * (NTOK * DIM);
    for (int u = tid; u < 2352; u += 384) {               // 49*192/4
        int e = u * 4;
        int r = e / 192, c = e % 192;
        float4 xv = *(const float4*)(xg + e);
        bf16x4 pk = { (bf16_t)xv.x, (bf16_t)xv.y, (bf16_t)xv.z, (bf16_t)xv.w };
        *(bf16x4*)(&sh_xo[r * 200 + c]) = pk;
    }

    // ---- bias table for this head (per-wave, no barrier needed) ----
    const float Dv = Dp[win];
    for (int u = lane; u < 169; u += 64) {
        int dr = u / 13 - 6, da = u % 13 - 6;
        int ri = (dr < 0) ? dr + 13 : dr;
        int ai = (da < 0) ? da + 13 : da;
        float ang_a = (float)da * (2.0f * PI_F / 56.0f);
        float ang_r = Dv * (float)dr * (2.0f * PI_F / 448.0f);
        bias13[u] = a_p[ai * NH + w] * __cosf(ang_a) + b_p[ai * NH + w] * __sinf(ang_a)
                  + a_r[ri * NH + w] * __cosf(ang_r) + b_r[ri * NH + w] * __sinf(ang_r);
    }
    __syncthreads();

    // lane-constant LDS row offsets for x/O fragment reads (rows >=49 clamp to 48;
    // those tokens are garbage-but-finite and masked/discarded downstream)
    int xoff[4];
#pragma unroll
    for (int mt = 0; mt < 4; ++mt) {
        int row = mt * 16 + l16;
        xoff[mt] = min(row, 48) * 200 + quad * 8;
    }

    // ---- Phase 1: QKV gemms ----
    // Q,K: swapped order -> acc[mt][ct]: channel = ct*16+quad*4+r, token = mt*16+l16
    const float scale = 0.17677669529663687f; // 32^-0.5
    int2 qp[4][2], kp[4][2];
    {
        const bf16_t* wgq = wq + (size_t)(w * 32) * DIM;
        const bf16_t* wgk = wq + (size_t)(DIM + w * 32) * DIM;
        f32x4 qa[4][2] = {}, ka[4][2] = {};
#pragma unroll
        for (int ks = 0; ks < 6; ++ks) {
            bf16x8 wq0 = *(const bf16x8*)(wgq + (size_t)l16 * DIM + ks * 32 + quad * 8);
            bf16x8 wq1 = *(const bf16x8*)(wgq + (size_t)(16 + l16) * DIM + ks * 32 + quad * 8);
            bf16x8 wk0 = *(const bf16x8*)(wgk + (size_t)l16 * DIM + ks * 32 + quad * 8);
            bf16x8 wk1 = *(const bf16x8*)(wgk + (size_t)(16 + l16) * DIM + ks * 32 + quad * 8);
#pragma unroll
            for (int mt = 0; mt < 4; ++mt) {
                bf16x8 xf = *(const bf16x8*)(&sh_xo[xoff[mt] + ks * 32]);
                qa[mt][0] = __builtin_amdgcn_mfma_f32_16x16x32_bf16(wq0, xf, qa[mt][0], 0, 0, 0);
                qa[mt][1] = __builtin_amdgcn_mfma_f32_16x16x32_bf16(wq1, xf, qa[mt][1], 0, 0, 0);
                ka[mt][0] = __builtin_amdgcn_mfma_f32_16x16x32_bf16(wk0, xf, ka[mt][0], 0, 0, 0);
                ka[mt][1] = __builtin_amdgcn_mfma_f32_16x16x32_bf16(wk1, xf, ka[mt][1], 0, 0, 0);
            }
        }
        float4 bq0 = *(const float4*)(qkv_b + w * 32 + quad * 4);
        float4 bq1 = *(const float4*)(qkv_b + w * 32 + 16 + quad * 4);
        float4 bk0 = *(const float4*)(qkv_b + DIM + w * 32 + quad * 4);
        float4 bk1 = *(const float4*)(qkv_b + DIM + w * 32 + 16 + quad * 4);
#pragma unroll
        for (int mt = 0; mt < 4; ++mt) {
            qp[mt][0] = pack4((qa[mt][0][0] + bq0.x) * scale, (qa[mt][0][1] + bq0.y) * scale,
                              (qa[mt][0][2] + bq0.z) * scale, (qa[mt][0][3] + bq0.w) * scale);
            qp[mt][1] = pack4((qa[mt][1][0] + bq1.x) * scale, (qa[mt][1][1] + bq1.y) * scale,
                              (qa[mt][1][2] + bq1.z) * scale, (qa[mt][1][3] + bq1.w) * scale);
            kp[mt][0] = pack4(ka[mt][0][0] + bk0.x, ka[mt][0][1] + bk0.y,
                              ka[mt][0][2] + bk0.z, ka[mt][0][3] + bk0.w);
            kp[mt][1] = pack4(ka[mt][1][0] + bk1.x, ka[mt][1][1] + bk1.y,
                              ka[mt][1][2] + bk1.z, ka[mt][1][3] + bk1.w);
        }
    }
    // V: standard order -> token = mt*16+quad*4+r, channel = ct*16+l16; write v^T LDS
    {
        const bf16_t* wgv = wq + (size_t)(2 * DIM + w * 32) * DIM;
        f32x4 va[4][2] = {};
#pragma unroll
        for (int ks = 0; ks < 6; ++ks) {
            bf16x8 wv0 = *(const bf16x8*)(wgv + (size_t)l16 * DIM + ks * 32 + quad * 8);
            bf16x8 wv1 = *(const bf16x8*)(wgv + (size_t)(16 + l16) * DIM + ks * 32 + quad * 8);
#pragma unroll
            for (int mt = 0; mt < 4; ++mt) {
                bf16x8 xf = *(const bf16x8*)(&sh_xo[xoff[mt] + ks * 32]);
                va[mt][0] = __builtin_amdgcn_mfma_f32_16x16x32_bf16(xf, wv0, va[mt][0], 0, 0, 0);
                va[mt][1] = __builtin_amdgcn_mfma_f32_16x16x32_bf16(xf, wv1, va[mt][1], 0, 0, 0);
            }
        }
        float bv0 = qkv_b[2 * DIM + w * 32 + l16];
        float bv1 = qkv_b[2 * DIM + w * 32 + 16 + l16];
#pragma unroll
        for (int mt = 0; mt < 4; ++mt) {
            *(int2*)(&vt[l16 * 72 + mt * 16 + quad * 4]) =
                pack4(va[mt][0][0] + bv0, va[mt][0][1] + bv0, va[mt][0][2] + bv0, va[mt][0][3] + bv0);
            *(int2*)(&vt[(16 + l16) * 72 + mt * 16 + quad * 4]) =
                pack4(va[mt][1][0] + bv1, va[mt][1][1] + bv1, va[mt][1][2] + bv1, va[mt][1][3] + bv1);
        }
    }

    // ---- fragment assembly (registers only; vt read is same-wave RAW) ----
    const int src_lo  = ((lane >> 4) & 1) * 32 + l16;   // (quad&1)*32 + l16
    const bool sel_hi = (lane & 32) != 0;               // quad>>1
    bf16x8 qf[4], kf[4];
#pragma unroll
    for (int t = 0; t < 4; ++t) {
        qf[t] = asm_frag(qp[t][0], qp[t][1], src_lo, sel_hi);   // lane l16 = token i, elem = d
        kf[t] = asm_frag(kp[t][0], kp[t][1], src_lo, sel_hi);   // lane l16 = token j, elem = d
    }
    bf16x8 vf[2][2];
#pragma unroll
    for (int ntd = 0; ntd < 2; ++ntd)
#pragma unroll
        for (int kt = 0; kt < 2; ++kt)
            vf[ntd][kt] = *(const bf16x8*)(&vt[(ntd * 16 + l16) * 72 + kt * 32 + quad * 8]);

    // per-lane j-codes: j = nt*16 + quad*4 + r, jcode = (j/7)*13 + j%7 (packed 8-bit)
    int jcp[4];
#pragma unroll
    for (int nt = 0; nt < 4; ++nt) {
        int p = 0;
#pragma unroll
        for (int r = 0; r < 4; ++r) {
            int j = nt * 16 + quad * 4 + r;
            p |= ((j / 7) * 13 + (j % 7)) << (8 * r);
        }
        jcp[nt] = p;
    }

    __syncthreads();   // all waves done reading x from sh_xo; O may now overwrite it

    // ---- Phase 2: attention, swapped QK^T (S^T: col i = l16, rows j in-lane) ----
    for (int mt = 0; mt < 4; ++mt) {
        f32x4 s[4] = {};
#pragma unroll
        for (int nt = 0; nt < 4; ++nt)
            s[nt] = __builtin_amdgcn_mfma_f32_16x16x32_bf16(kf[nt], qf[mt], s[nt], 0, 0, 0);

        int i = mt * 16 + l16;
        int icl = min(i, 48);
        int icode = (icl / 7) * 13 + (icl % 7) + 84;

        float val[4][4];
        float mx = -1e30f;
#pragma unroll
        for (int nt = 0; nt < 4; ++nt)
#pragma unroll
            for (int r = 0; r < 4; ++r) {
                int j = nt * 16 + quad * 4 + r;
                int idx = icode - ((jcp[nt] >> (8 * r)) & 255);
                idx = max(idx, 0);
                float vv = s[nt][r] + bias13[idx];
                vv = (j < 49) ? vv : -1e30f;
                val[nt][r] = vv;
                mx = fmaxf(mx, vv);
            }
        mx = fmaxf(mx, __shfl_xor(mx, 16));
        mx = fmaxf(mx, __shfl_xor(mx, 32));
        float sum = 0.f;
#pragma unroll
        for (int nt = 0; nt < 4; ++nt)
#pragma unroll
            for (int r = 0; r < 4; ++r) {
                float e = __expf(val[nt][r] - mx);
                val[nt][r] = e;
                sum += e;
            }
        sum += __shfl_xor(sum, 16);
        sum += __shfl_xor(sum, 32);
        float rs = 1.0f / sum;

        // P^T fragments in registers (col i = l16, k = j)
        int2 pv0 = pack4(val[0][0], val[0][1], val[0][2], val[0][3]);
        int2 pv1 = pack4(val[1][0], val[1][1], val[1][2], val[1][3]);
        int2 pv2 = pack4(val[2][0], val[2][1], val[2][2], val[2][3]);
        int2 pv3 = pack4(val[3][0], val[3][1], val[3][2], val[3][3]);
        bf16x8 pT0 = asm_frag(pv0, pv1, src_lo, sel_hi);
        bf16x8 pT1 = asm_frag(pv2, pv3, src_lo, sel_hi);

        // O^T = V^T * P^T : rows d (in-lane), col i = l16
        f32x4 o0 = {}, o1 = {};
        o0 = __builtin_amdgcn_mfma_f32_16x16x32_bf16(vf[0][0], pT0, o0, 0, 0, 0);
        o0 = __builtin_amdgcn_mfma_f32_16x16x32_bf16(vf[0][1], pT1, o0, 0, 0, 0);
        o1 = __builtin_amdgcn_mfma_f32_16x16x32_bf16(vf[1][0], pT0, o1, 0, 0, 0);
        o1 = __builtin_amdgcn_mfma_f32_16x16x32_bf16(vf[1][1], pT1, o1, 0, 0, 0);

        if (i < 49) {
            *(int2*)(&sh_xo[i * 200 + w * 32 + quad * 4]) =
                pack4(o0[0] * rs, o0[1] * rs, o0[2] * rs, o0[3] * rs);
            *(int2*)(&sh_xo[i * 200 + w * 32 + 16 + quad * 4]) =
                pack4(o1[0] * rs, o1[1] * rs, o1[2] * rs, o1[3] * rs);
        }
    }

    __syncthreads();   // all heads' O written into sh_xo

    // ---- Phase 3: output projection; wave w covers out channels [w*32, w*32+32) ----
    bf16x8 wf[2][6];
#pragma unroll
    for (int nt = 0; nt < 2; ++nt)
#pragma unroll
        for (int ks = 0; ks < 6; ++ks)
            wf[nt][ks] = *(const bf16x8*)(wp + (size_t)(w * 32 + nt * 16 + l16) * DIM + ks * 32 + quad * 8);

    f32x4 pacc[4][2] = {};
#pragma unroll
    for (int mt = 0; mt < 4; ++mt)
#pragma unroll
        for (int ks = 0; ks < 6; ++ks) {
            bf16x8 oa = *(const bf16x8*)(&sh_xo[xoff[mt] + ks * 32]);
            pacc[mt][0] = __builtin_amdgcn_mfma_f32_16x16x32_bf16(oa, wf[0][ks], pacc[mt][0], 0, 0, 0);
            pacc[mt][1] = __builtin_amdgcn_mfma_f32_16x16x32_bf16(oa, wf[1][ks], pacc[mt][1], 0, 0, 0);
        }

    float pb0 = proj_b[w * 32 + l16];
    float pb1 = proj_b[w * 32 + 16 + l16];
#pragma unroll
    for (int mt = 0; mt < 4; ++mt)
#pragma unroll
        for (int r = 0; r < 4; ++r) {
            int i = mt * 16 + quad * 4 + r;
            if (i < 49) {
                float* op = out + ((size_t)win * NTOK + i) * DIM + w * 32;
                op[l16]      = pacc[mt][0][r] + pb0;
                op[16 + l16] = pacc[mt][1][r] + pb1;
            }
        }
}

extern "C" void kernel_launch(void* const* d_in, const int* in_sizes, int n_in,
                              void* d_out, int out_size, void* d_ws, size_t ws_size,
                              hipStream_t stream) {
    const float* x      = (const float*)d_in[0];
    const float* D      = (const float*)d_in[1];
    const float* qkv_w  = (const float*)d_in[2];
    const float* qkv_b  = (const float*)d_in[3];
    const float* proj_w = (const float*)d_in[4];
    const float* proj_b = (const float*)d_in[5];
    const float* a_p    = (const float*)d_in[6];
    const float* b_p    = (const float*)d_in[7];
    const float* a_r    = (const float*)d_in[8];
    const float* b_r    = (const float*)d_in[9];
    float* out = (float*)d_out;

    const int B_ = in_sizes[0] / (NTOK * DIM);   // 2048 windows

    char* wsp = (char*)d_ws;
    bf16_t* wq = (bf16_t*)wsp; wsp += (size_t)QKV_DIM * DIM * 2;
    bf16_t* wp = (bf16_t*)wsp;

    cvt_weights<<<dim3((QKV_DIM * DIM + DIM * DIM + 255) / 256), dim3(256), 0, stream>>>(
        qkv_w, proj_w, wq, wp);

    fused_win_attn<<<dim3(B_), dim3(384), 0, stream>>>(
        x, D, wq, qkv_b, wp, proj_b, a_p, b_p, a_r, b_r, out);
}

// Round 2
// 295.648 us; speedup vs baseline: 1.0235x; 1.0235x over previous
//
#include <hip/hip_runtime.h>

#define NTOK 49
#define NH 6
#define HD 32
#define DIM 192
#define QKV_DIM 576
#define PI_F 3.14159265358979323846f
#define XSTR 204   // sh_xo row stride in bf16: 408B = 102dw, 102 mod 32 = 6 (gcd 2) -> conflict-minimal b128 reads

typedef __bf16 bf16_t;
typedef __bf16 bf16x4 __attribute__((ext_vector_type(4)));
typedef __bf16 bf16x8 __attribute__((ext_vector_type(8)));
typedef float f32x4 __attribute__((ext_vector_type(4)));

// ---------------- Kernel 0: convert weights fp32 -> bf16 ----------------
__global__ __launch_bounds__(256) void cvt_weights(const float* __restrict__ qkv_w,
                                                   const float* __restrict__ proj_w,
                                                   bf16_t* __restrict__ wq,
                                                   bf16_t* __restrict__ wp) {
    int idx = blockIdx.x * 256 + threadIdx.x;
    if (idx < QKV_DIM * DIM) {
        wq[idx] = (bf16_t)qkv_w[idx];
    } else {
        int j = idx - QKV_DIM * DIM;
        if (j < DIM * DIM) wp[j] = (bf16_t)proj_w[j];
    }
}

// pack 4 floats into bf16x4 viewed as int2 (regs r0..r3)
__device__ __forceinline__ int2 pack4(float a, float b, float c, float d) {
    bf16x4 t = { (bf16_t)a, (bf16_t)b, (bf16_t)c, (bf16_t)d };
    union { bf16x4 v; int2 i; } u;
    u.v = t;
    return u.i;
}

// Cross-quad fragment assembly (verified R1).
// Source: packed tiles p0 (tile base) / p1 (base+1); lane (qs,l16) reg r holds
//   elem [qs*4+r] of its tile at col l16.
// Target A/B-fragment: lane (q,l16) elem e = tile (q>>1), idx = (q&1)*8+e.
__device__ __forceinline__ bf16x8 asm_frag(int2 p0, int2 p1, int src_lo, bool sel_hi) {
    int a0x = __shfl(p0.x, src_lo),      a0y = __shfl(p0.y, src_lo);
    int a1x = __shfl(p0.x, src_lo + 16), a1y = __shfl(p0.y, src_lo + 16);
    int b0x = __shfl(p1.x, src_lo),      b0y = __shfl(p1.y, src_lo);
    int b1x = __shfl(p1.x, src_lo + 16), b1y = __shfl(p1.y, src_lo + 16);
    union { int x[4]; bf16x8 v; } u;
    u.x[0] = sel_hi ? b0x : a0x;
    u.x[1] = sel_hi ? b0y : a0y;
    u.x[2] = sel_hi ? b1x : a1x;
    u.x[3] = sel_hi ? b1y : a1y;
    return u.v;
}

// ---------------- Kernel 1: fully-fused window attention ----------------
// TWO windows per block (768 thr = 12 waves). Wave w: window wb=w/6, head h=w%6.
// R1 showed the scheduler keeps only ONE workgroup of this kernel per CU no
// matter how small LDS/VGPR get; so we pack 12 waves into that one workgroup
// to force occupancy up. Q, K, V and P all live in registers (asm_frag repack);
// LDS is only x/O staging (stride-204 anti-conflict) + bias tables (~47 KB).
__global__ __launch_bounds__(768, 3) void fused_win_attn(
        const float* __restrict__ x,
        const float* __restrict__ Dp,
        const bf16_t* __restrict__ wq,
        const float* __restrict__ qkv_b,
        const bf16_t* __restrict__ wp,
        const float* __restrict__ proj_b,
        const float* __restrict__ a_p,
        const float* __restrict__ b_p,
        const float* __restrict__ a_r,
        const float* __restrict__ b_r,
        float* __restrict__ out,
        int nwin) {
    __shared__ __align__(16) bf16_t sh_xo[2][49 * XSTR];   // x, later O (2 x 20.0 KB)
    __shared__ float bias_sh[12][169];                     // per (window,head) (8.1 KB)

    const int tid  = threadIdx.x;
    const int w    = tid >> 6;        // wave id 0..11
    const int lane = tid & 63;
    const int l16  = lane & 15;
    const int quad = lane >> 4;
    const int wb   = w / 6;           // window sub-slot
    const int h    = w % 6;           // head
    const int win  = blockIdx.x * 2 + wb;
    const int winc = min(win, nwin - 1);
    const bool alive = (win < nwin);

    bf16_t* xl     = sh_xo[wb];
    float*  bias13 = bias_sh[w];

    // ---- Phase 0: stage x for both windows (49x192 fp32 -> bf16 LDS) ----
    for (int u = tid; u < 4704; u += 768) {               // 2*49*192/4
        int wbs = (u >= 2352) ? 1 : 0;
        int e = (u - wbs * 2352) * 4;
        int r = e / 192, c = e % 192;
        int wsrc = min(blockIdx.x * 2 + wbs, nwin - 1);
        float4 xv = *(const float4*)(x + (size_t)wsrc * (NTOK * DIM) + e);
        bf16x4 pk = { (bf16_t)xv.x, (bf16_t)xv.y, (bf16_t)xv.z, (bf16_t)xv.w };
        *(bf16x4*)(&sh_xo[wbs][r * XSTR + c]) = pk;
    }

    // ---- bias table for this (window, head) (written/read by same wave) ----
    const float Dv = Dp[winc];
    for (int u = lane; u < 169; u += 64) {
        int dr = u / 13 - 6, da = u % 13 - 6;
        int ri = (dr < 0) ? dr + 13 : dr;
        int ai = (da < 0) ? da + 13 : da;
        float ang_a = (float)da * (2.0f * PI_F / 56.0f);
        float ang_r = Dv * (float)dr * (2.0f * PI_F / 448.0f);
        bias13[u] = a_p[ai * NH + h] * __cosf(ang_a) + b_p[ai * NH + h] * __sinf(ang_a)
                  + a_r[ri * NH + h] * __cosf(ang_r) + b_r[ri * NH + h] * __sinf(ang_r);
    }
    __syncthreads();

    // lane-constant LDS row offsets for x/O fragment reads (rows >=49 clamp to 48)
    int xoff[4];
#pragma unroll
    for (int mt = 0; mt < 4; ++mt) {
        int row = mt * 16 + l16;
        xoff[mt] = min(row, 48) * XSTR + quad * 8;
    }

    const int src_lo  = ((lane >> 4) & 1) * 32 + l16;   // (quad&1)*32 + l16
    const bool sel_hi = (lane & 32) != 0;               // quad>>1

    // ---- Phase 1a: Q,K gemms (swapped order: channel in-lane, token = l16) ----
    const float scale = 0.17677669529663687f; // 32^-0.5
    int2 qp[4][2], kp[4][2];
    {
        const bf16_t* wgq = wq + (size_t)(h * 32) * DIM;
        const bf16_t* wgk = wq + (size_t)(DIM + h * 32) * DIM;
        f32x4 qa[4][2] = {}, ka[4][2] = {};
#pragma unroll
        for (int ks = 0; ks < 6; ++ks) {
            bf16x8 wq0 = *(const bf16x8*)(wgq + (size_t)l16 * DIM + ks * 32 + quad * 8);
            bf16x8 wq1 = *(const bf16x8*)(wgq + (size_t)(16 + l16) * DIM + ks * 32 + quad * 8);
            bf16x8 wk0 = *(const bf16x8*)(wgk + (size_t)l16 * DIM + ks * 32 + quad * 8);
            bf16x8 wk1 = *(const bf16x8*)(wgk + (size_t)(16 + l16) * DIM + ks * 32 + quad * 8);
#pragma unroll
            for (int mt = 0; mt < 4; ++mt) {
                bf16x8 xf = *(const bf16x8*)(&xl[xoff[mt] + ks * 32]);
                qa[mt][0] = __builtin_amdgcn_mfma_f32_16x16x32_bf16(wq0, xf, qa[mt][0], 0, 0, 0);
                qa[mt][1] = __builtin_amdgcn_mfma_f32_16x16x32_bf16(wq1, xf, qa[mt][1], 0, 0, 0);
                ka[mt][0] = __builtin_amdgcn_mfma_f32_16x16x32_bf16(wk0, xf, ka[mt][0], 0, 0, 0);
                ka[mt][1] = __builtin_amdgcn_mfma_f32_16x16x32_bf16(wk1, xf, ka[mt][1], 0, 0, 0);
            }
        }
        float4 bq0 = *(const float4*)(qkv_b + h * 32 + quad * 4);
        float4 bq1 = *(const float4*)(qkv_b + h * 32 + 16 + quad * 4);
        float4 bk0 = *(const float4*)(qkv_b + DIM + h * 32 + quad * 4);
        float4 bk1 = *(const float4*)(qkv_b + DIM + h * 32 + 16 + quad * 4);
#pragma unroll
        for (int mt = 0; mt < 4; ++mt) {
            qp[mt][0] = pack4((qa[mt][0][0] + bq0.x) * scale, (qa[mt][0][1] + bq0.y) * scale,
                              (qa[mt][0][2] + bq0.z) * scale, (qa[mt][0][3] + bq0.w) * scale);
            qp[mt][1] = pack4((qa[mt][1][0] + bq1.x) * scale, (qa[mt][1][1] + bq1.y) * scale,
                              (qa[mt][1][2] + bq1.z) * scale, (qa[mt][1][3] + bq1.w) * scale);
            kp[mt][0] = pack4(ka[mt][0][0] + bk0.x, ka[mt][0][1] + bk0.y,
                              ka[mt][0][2] + bk0.z, ka[mt][0][3] + bk0.w);
            kp[mt][1] = pack4(ka[mt][1][0] + bk1.x, ka[mt][1][1] + bk1.y,
                              ka[mt][1][2] + bk1.z, ka[mt][1][3] + bk1.w);
        }
    }

    // ---- Phase 1b: V gemm (standard order: token in-lane, channel = l16) ----
    int2 vp[4][2];
    {
        const bf16_t* wgv = wq + (size_t)(2 * DIM + h * 32) * DIM;
        f32x4 va[4][2] = {};
#pragma unroll
        for (int ks = 0; ks < 6; ++ks) {
            bf16x8 wv0 = *(const bf16x8*)(wgv + (size_t)l16 * DIM + ks * 32 + quad * 8);
            bf16x8 wv1 = *(const bf16x8*)(wgv + (size_t)(16 + l16) * DIM + ks * 32 + quad * 8);
#pragma unroll
            for (int mt = 0; mt < 4; ++mt) {
                bf16x8 xf = *(const bf16x8*)(&xl[xoff[mt] + ks * 32]);
                va[mt][0] = __builtin_amdgcn_mfma_f32_16x16x32_bf16(xf, wv0, va[mt][0], 0, 0, 0);
                va[mt][1] = __builtin_amdgcn_mfma_f32_16x16x32_bf16(xf, wv1, va[mt][1], 0, 0, 0);
            }
        }
        float bv0 = qkv_b[2 * DIM + h * 32 + l16];
        float bv1 = qkv_b[2 * DIM + h * 32 + 16 + l16];
#pragma unroll
        for (int mt = 0; mt < 4; ++mt) {
            vp[mt][0] = pack4(va[mt][0][0] + bv0, va[mt][0][1] + bv0,
                              va[mt][0][2] + bv0, va[mt][0][3] + bv0);
            vp[mt][1] = pack4(va[mt][1][0] + bv1, va[mt][1][1] + bv1,
                              va[mt][1][2] + bv1, va[mt][1][3] + bv1);
        }
    }

    // ---- fragment assembly (registers only) ----
    bf16x8 qf[4], kf[4];
#pragma unroll
    for (int t = 0; t < 4; ++t) {
        qf[t] = asm_frag(qp[t][0], qp[t][1], src_lo, sel_hi);   // row l16 = token i, elems = d
        kf[t] = asm_frag(kp[t][0], kp[t][1], src_lo, sel_hi);   // row l16 = token j, elems = d
    }
    // V^T fragments: row l16 = channel (ntd half), elems = tokens (kt*32 + quad*8 + e)
    bf16x8 vf[2][2];
#pragma unroll
    for (int kt = 0; kt < 2; ++kt)
#pragma unroll
        for (int ntd = 0; ntd < 2; ++ntd)
            vf[ntd][kt] = asm_frag(vp[2 * kt][ntd], vp[2 * kt + 1][ntd], src_lo, sel_hi);

    // per-lane j-codes: j = nt*16 + quad*4 + r, jcode = (j/7)*13 + j%7 (packed 8-bit)
    int jcp[4];
#pragma unroll
    for (int nt = 0; nt < 4; ++nt) {
        int p = 0;
#pragma unroll
        for (int r = 0; r < 4; ++r) {
            int j = nt * 16 + quad * 4 + r;
            p |= ((j / 7) * 13 + (j % 7)) << (8 * r);
        }
        jcp[nt] = p;
    }

    __syncthreads();   // all waves done reading x from sh_xo; O may now overwrite

    // ---- Phase 2: attention, swapped QK^T (S^T: col i = l16, rows j in-lane) ----
    for (int mt = 0; mt < 4; ++mt) {
        f32x4 s[4] = {};
#pragma unroll
        for (int nt = 0; nt < 4; ++nt)
            s[nt] = __builtin_amdgcn_mfma_f32_16x16x32_bf16(kf[nt], qf[mt], s[nt], 0, 0, 0);

        int i = mt * 16 + l16;
        int icl = min(i, 48);
        int icode = (icl / 7) * 13 + (icl % 7) + 84;

        float val[4][4];
        float mx = -1e30f;
#pragma unroll
        for (int nt = 0; nt < 4; ++nt)
#pragma unroll
            for (int r = 0; r < 4; ++r) {
                int j = nt * 16 + quad * 4 + r;
                int idx = icode - ((jcp[nt] >> (8 * r)) & 255);
                idx = max(idx, 0);
                float vv = s[nt][r] + bias13[idx];
                vv = (j < 49) ? vv : -1e30f;
                val[nt][r] = vv;
                mx = fmaxf(mx, vv);
            }
        mx = fmaxf(mx, __shfl_xor(mx, 16));
        mx = fmaxf(mx, __shfl_xor(mx, 32));
        float sum = 0.f;
#pragma unroll
        for (int nt = 0; nt < 4; ++nt)
#pragma unroll
            for (int r = 0; r < 4; ++r) {
                float e = __expf(val[nt][r] - mx);
                val[nt][r] = e;
                sum += e;
            }
        sum += __shfl_xor(sum, 16);
        sum += __shfl_xor(sum, 32);
        float rs = 1.0f / sum;

        // P^T fragments in registers (col i = l16, k = j)
        int2 pv0 = pack4(val[0][0], val[0][1], val[0][2], val[0][3]);
        int2 pv1 = pack4(val[1][0], val[1][1], val[1][2], val[1][3]);
        int2 pv2 = pack4(val[2][0], val[2][1], val[2][2], val[2][3]);
        int2 pv3 = pack4(val[3][0], val[3][1], val[3][2], val[3][3]);
        bf16x8 pT0 = asm_frag(pv0, pv1, src_lo, sel_hi);
        bf16x8 pT1 = asm_frag(pv2, pv3, src_lo, sel_hi);

        // O^T = V^T * P^T : rows d (in-lane), col i = l16
        f32x4 o0 = {}, o1 = {};
        o0 = __builtin_amdgcn_mfma_f32_16x16x32_bf16(vf[0][0], pT0, o0, 0, 0, 0);
        o0 = __builtin_amdgcn_mfma_f32_16x16x32_bf16(vf[0][1], pT1, o0, 0, 0, 0);
        o1 = __builtin_amdgcn_mfma_f32_16x16x32_bf16(vf[1][0], pT0, o1, 0, 0, 0);
        o1 = __builtin_amdgcn_mfma_f32_16x16x32_bf16(vf[1][1], pT1, o1, 0, 0, 0);

        if (i < 49) {
            *(int2*)(&xl[i * XSTR + h * 32 + quad * 4]) =
                pack4(o0[0] * rs, o0[1] * rs, o0[2] * rs, o0[3] * rs);
            *(int2*)(&xl[i * XSTR + h * 32 + 16 + quad * 4]) =
                pack4(o1[0] * rs, o1[1] * rs, o1[2] * rs, o1[3] * rs);
        }
    }

    __syncthreads();   // all heads' O written into sh_xo

    // ---- Phase 3: output projection; wave w covers out channels [h*32, h*32+32) ----
    bf16x8 wf[2][6];
#pragma unroll
    for (int nt = 0; nt < 2; ++nt)
#pragma unroll
        for (int ks = 0; ks < 6; ++ks)
            wf[nt][ks] = *(const bf16x8*)(wp + (size_t)(h * 32 + nt * 16 + l16) * DIM + ks * 32 + quad * 8);

    f32x4 pacc[4][2] = {};
#pragma unroll
    for (int mt = 0; mt < 4; ++mt)
#pragma unroll
        for (int ks = 0; ks < 6; ++ks) {
            bf16x8 oa = *(const bf16x8*)(&xl[xoff[mt] + ks * 32]);
            pacc[mt][0] = __builtin_amdgcn_mfma_f32_16x16x32_bf16(oa, wf[0][ks], pacc[mt][0], 0, 0, 0);
            pacc[mt][1] = __builtin_amdgcn_mfma_f32_16x16x32_bf16(oa, wf[1][ks], pacc[mt][1], 0, 0, 0);
        }

    float pb0 = proj_b[h * 32 + l16];
    float pb1 = proj_b[h * 32 + 16 + l16];
#pragma unroll
    for (int mt = 0; mt < 4; ++mt)
#pragma unroll
        for (int r = 0; r < 4; ++r) {
            int i = mt * 16 + quad * 4 + r;
            if (alive && i < 49) {
                float* op = out + ((size_t)win * NTOK + i) * DIM + h * 32;
                op[l16]      = pacc[mt][0][r] + pb0;
                op[16 + l16] = pacc[mt][1][r] + pb1;
            }
        }
}

extern "C" void kernel_launch(void* const* d_in, const int* in_sizes, int n_in,
                              void* d_out, int out_size, void* d_ws, size_t ws_size,
                              hipStream_t stream) {
    const float* x      = (const float*)d_in[0];
    const float* D      = (const float*)d_in[1];
    const float* qkv_w  = (const float*)d_in[2];
    const float* qkv_b  = (const float*)d_in[3];
    const float* proj_w = (const float*)d_in[4];
    const float* proj_b = (const float*)d_in[5];
    const float* a_p    = (const float*)d_in[6];
    const float* b_p    = (const float*)d_in[7];
    const float* a_r    = (const float*)d_in[8];
    const float* b_r    = (const float*)d_in[9];
    float* out = (float*)d_out;

    const int B_ = in_sizes[0] / (NTOK * DIM);   // 2048 windows

    char* wsp = (char*)d_ws;
    bf16_t* wq = (bf16_t*)wsp; wsp += (size_t)QKV_DIM * DIM * 2;
    bf16_t* wp = (bf16_t*)wsp;

    cvt_weights<<<dim3((QKV_DIM * DIM + DIM * DIM + 255) / 256), dim3(256), 0, stream>>>(
        qkv_w, proj_w, wq, wp);

    fused_win_attn<<<dim3((B_ + 1) / 2), dim3(768), 0, stream>>>(
        x, D, wq, qkv_b, wp, proj_b, a_p, b_p, a_r, b_r, out, B_);
}

// Round 3
// 254.678 us; speedup vs baseline: 1.1882x; 1.1609x over previous
//
#include <hip/hip_runtime.h>

#define NTOK 49
#define NH 6
#define DIM 192
#define QKV_DIM 576
#define PI_F 3.14159265358979323846f

typedef __bf16 bf16_t;
typedef __bf16 bf16x4 __attribute__((ext_vector_type(4)));
typedef __bf16 bf16x8 __attribute__((ext_vector_type(8)));
typedef float f32x4 __attribute__((ext_vector_type(4)));
typedef short s16x4 __attribute__((ext_vector_type(4)));

// ---------------- Kernel 0: convert weights fp32 -> bf16 ----------------
__global__ __launch_bounds__(256) void cvt_weights(const float* __restrict__ qkv_w,
                                                   const float* __restrict__ proj_w,
                                                   bf16_t* __restrict__ wq,
                                                   bf16_t* __restrict__ wp) {
    int idx = blockIdx.x * 256 + threadIdx.x;
    if (idx < QKV_DIM * DIM) {
        wq[idx] = (bf16_t)qkv_w[idx];
    } else {
        int j = idx - QKV_DIM * DIM;
        if (j < DIM * DIM) wp[j] = (bf16_t)proj_w[j];
    }
}

// 16B-block XOR swizzle for the x/O LDS tile (stride DIM=192 elems, no pad).
// Bank start of (r, block g) = 4*((g ^ (r&7)) & 7): rows spread over 8 bank
// groups -> max 2-way (free) conflict on b128/b64 accesses; 16B-aligned always.
__device__ __forceinline__ int swz(int r, int c) {
    return r * DIM + (((c >> 3) ^ (r & 7)) << 3) + (c & 7);
}

// pack 4 floats -> 4 bf16 viewed as short4 (ready-made 16x16x16 MFMA fragment)
__device__ __forceinline__ s16x4 pack4s(float a, float b, float c, float d) {
    bf16x4 t = { (bf16_t)a, (bf16_t)b, (bf16_t)c, (bf16_t)d };
    union { bf16x4 v; s16x4 s; } u;
    u.v = t;
    return u.s;
}

// ---------------- Kernel 1: fully-fused window attention ----------------
// TWO windows per block (768 thr = 12 waves). Wave w: window wb=w/6, head h=w%6.
// R2 showed the DS pipe is the saturated resource (~324 DS ops/wave, occupancy
// doubling gave +4%). This version deletes ALL cross-lane repack (160 bpermutes)
// by using v_mfma_f32_16x16x16_bf16 for attention: the QKV gemm D-layout
// (value at [l16-col][quad*4+r row]) IS the x16 A/B fragment layout, so Q/K/V/P
// feed MFMA directly from registers. LDS = swizzled x/O tile + bias (~46 KB).
__global__ __launch_bounds__(768, 3) void fused_win_attn(
        const float* __restrict__ x,
        const float* __restrict__ Dp,
        const bf16_t* __restrict__ wq,
        const float* __restrict__ qkv_b,
        const bf16_t* __restrict__ wp,
        const float* __restrict__ proj_b,
        const float* __restrict__ a_p,
        const float* __restrict__ b_p,
        const float* __restrict__ a_r,
        const float* __restrict__ b_r,
        float* __restrict__ out,
        int nwin) {
    __shared__ __align__(16) bf16_t sh_xo[2][NTOK * DIM];   // x, later O (2 x 18.4 KB)
    __shared__ float bias_sh[12][169];                      // per (window,head) (8.1 KB)

    const int tid  = threadIdx.x;
    const int w    = tid >> 6;        // wave id 0..11
    const int lane = tid & 63;
    const int l16  = lane & 15;
    const int quad = lane >> 4;
    const int wb   = w / 6;           // window sub-slot
    const int h    = w % 6;           // head
    const int win  = blockIdx.x * 2 + wb;
    const int winc = min(win, nwin - 1);
    const bool alive = (win < nwin);

    bf16_t* xl     = sh_xo[wb];
    float*  bias13 = bias_sh[w];

    // ---- Phase 0: stage x for both windows (49x192 fp32 -> bf16 LDS, swizzled) ----
    for (int u = tid; u < 4704; u += 768) {               // 2*49*192/4
        int wbs = (u >= 2352) ? 1 : 0;
        int e = (u - wbs * 2352) * 4;
        int r = e / 192, c = e % 192;
        int wsrc = min(blockIdx.x * 2 + wbs, nwin - 1);
        float4 xv = *(const float4*)(x + (size_t)wsrc * (NTOK * DIM) + e);
        bf16x4 pk = { (bf16_t)xv.x, (bf16_t)xv.y, (bf16_t)xv.z, (bf16_t)xv.w };
        *(bf16x4*)(&sh_xo[wbs][swz(r, c)]) = pk;
    }

    // ---- bias table for this (window, head) (written/read by same wave) ----
    const float Dv = Dp[winc];
    for (int u = lane; u < 169; u += 64) {
        int dr = u / 13 - 6, da = u % 13 - 6;
        int ri = (dr < 0) ? dr + 13 : dr;
        int ai = (da < 0) ? da + 13 : da;
        float ang_a = (float)da * (2.0f * PI_F / 56.0f);
        float ang_r = Dv * (float)dr * (2.0f * PI_F / 448.0f);
        bias13[u] = a_p[ai * NH + h] * __cosf(ang_a) + b_p[ai * NH + h] * __sinf(ang_a)
                  + a_r[ri * NH + h] * __cosf(ang_r) + b_r[ri * NH + h] * __sinf(ang_r);
    }
    __syncthreads();

    // clamped token rows for fragment reads (rows >=49 clamp to 48, masked later)
    int rowc[4];
#pragma unroll
    for (int mt = 0; mt < 4; ++mt)
        rowc[mt] = min(mt * 16 + l16, 48);

    // ---- Phase 1: merged Q/K/V gemms (single pass over x fragments) ----
    // Q,K swapped order (W as A): D = [channel rows in-lane][token col = l16]
    // V standard order (x as A):  D = [token rows in-lane][channel col = l16]
    const float scale = 0.17677669529663687f; // 32^-0.5
    s16x4 qp[4][2], kp[4][2], vp[4][2];
    {
        const bf16_t* wgq = wq + (size_t)(h * 32) * DIM;
        const bf16_t* wgk = wq + (size_t)(DIM + h * 32) * DIM;
        const bf16_t* wgv = wq + (size_t)(2 * DIM + h * 32) * DIM;
        f32x4 qa[4][2] = {}, ka[4][2] = {}, va[4][2] = {};
#pragma unroll
        for (int ks = 0; ks < 6; ++ks) {
            bf16x8 wq0 = *(const bf16x8*)(wgq + (size_t)l16 * DIM + ks * 32 + quad * 8);
            bf16x8 wq1 = *(const bf16x8*)(wgq + (size_t)(16 + l16) * DIM + ks * 32 + quad * 8);
            bf16x8 wk0 = *(const bf16x8*)(wgk + (size_t)l16 * DIM + ks * 32 + quad * 8);
            bf16x8 wk1 = *(const bf16x8*)(wgk + (size_t)(16 + l16) * DIM + ks * 32 + quad * 8);
            bf16x8 wv0 = *(const bf16x8*)(wgv + (size_t)l16 * DIM + ks * 32 + quad * 8);
            bf16x8 wv1 = *(const bf16x8*)(wgv + (size_t)(16 + l16) * DIM + ks * 32 + quad * 8);
#pragma unroll
            for (int mt = 0; mt < 4; ++mt) {
                bf16x8 xf = *(const bf16x8*)(&xl[swz(rowc[mt], ks * 32 + quad * 8)]);
                qa[mt][0] = __builtin_amdgcn_mfma_f32_16x16x32_bf16(wq0, xf, qa[mt][0], 0, 0, 0);
                qa[mt][1] = __builtin_amdgcn_mfma_f32_16x16x32_bf16(wq1, xf, qa[mt][1], 0, 0, 0);
                ka[mt][0] = __builtin_amdgcn_mfma_f32_16x16x32_bf16(wk0, xf, ka[mt][0], 0, 0, 0);
                ka[mt][1] = __builtin_amdgcn_mfma_f32_16x16x32_bf16(wk1, xf, ka[mt][1], 0, 0, 0);
                va[mt][0] = __builtin_amdgcn_mfma_f32_16x16x32_bf16(xf, wv0, va[mt][0], 0, 0, 0);
                va[mt][1] = __builtin_amdgcn_mfma_f32_16x16x32_bf16(xf, wv1, va[mt][1], 0, 0, 0);
            }
        }
        float4 bq0 = *(const float4*)(qkv_b + h * 32 + quad * 4);
        float4 bq1 = *(const float4*)(qkv_b + h * 32 + 16 + quad * 4);
        float4 bk0 = *(const float4*)(qkv_b + DIM + h * 32 + quad * 4);
        float4 bk1 = *(const float4*)(qkv_b + DIM + h * 32 + 16 + quad * 4);
        float bv0 = qkv_b[2 * DIM + h * 32 + l16];
        float bv1 = qkv_b[2 * DIM + h * 32 + 16 + l16];
#pragma unroll
        for (int mt = 0; mt < 4; ++mt) {
            // qp/kp[token-tile][d-half]: B/A frags, lane holds [d=quad*4+r][tok=l16]
            qp[mt][0] = pack4s((qa[mt][0][0] + bq0.x) * scale, (qa[mt][0][1] + bq0.y) * scale,
                               (qa[mt][0][2] + bq0.z) * scale, (qa[mt][0][3] + bq0.w) * scale);
            qp[mt][1] = pack4s((qa[mt][1][0] + bq1.x) * scale, (qa[mt][1][1] + bq1.y) * scale,
                               (qa[mt][1][2] + bq1.z) * scale, (qa[mt][1][3] + bq1.w) * scale);
            kp[mt][0] = pack4s(ka[mt][0][0] + bk0.x, ka[mt][0][1] + bk0.y,
                               ka[mt][0][2] + bk0.z, ka[mt][0][3] + bk0.w);
            kp[mt][1] = pack4s(ka[mt][1][0] + bk1.x, ka[mt][1][1] + bk1.y,
                               ka[mt][1][2] + bk1.z, ka[mt][1][3] + bk1.w);
            // vp[token-tile][d-half]: V^T A-frag, lane holds [d=l16][tok=quad*4+r]
            vp[mt][0] = pack4s(va[mt][0][0] + bv0, va[mt][0][1] + bv0,
                               va[mt][0][2] + bv0, va[mt][0][3] + bv0);
            vp[mt][1] = pack4s(va[mt][1][0] + bv1, va[mt][1][1] + bv1,
                               va[mt][1][2] + bv1, va[mt][1][3] + bv1);
        }
    }

    // per-lane j-codes: j = nt*16 + quad*4 + r, jcode = (j/7)*13 + j%7 (packed 8-bit)
    int jcp[4];
#pragma unroll
    for (int nt = 0; nt < 4; ++nt) {
        int p = 0;
#pragma unroll
        for (int r = 0; r < 4; ++r) {
            int j = nt * 16 + quad * 4 + r;
            p |= ((j / 7) * 13 + (j % 7)) << (8 * r);
        }
        jcp[nt] = p;
    }

    // hoist proj weights early (VMEM latency overlaps attention compute)
    bf16x8 wf[2][6];
#pragma unroll
    for (int nt = 0; nt < 2; ++nt)
#pragma unroll
        for (int ks = 0; ks < 6; ++ks)
            wf[nt][ks] = *(const bf16x8*)(wp + (size_t)(h * 32 + nt * 16 + l16) * DIM + ks * 32 + quad * 8);

    __syncthreads();   // all waves done reading x from sh_xo; O may now overwrite

    // ---- Phase 2: attention via 16x16x16 MFMA, zero cross-lane repack ----
    // S^T tile = mfma16(K-frag, Q-frag): S^T[j=nt*16+quad*4+r][i=mt*16+l16]
    for (int mt = 0; mt < 4; ++mt) {
        f32x4 s[4] = {};
#pragma unroll
        for (int nt = 0; nt < 4; ++nt) {
            s[nt] = __builtin_amdgcn_mfma_f32_16x16x16bf16_1k(kp[nt][0], qp[mt][0], s[nt], 0, 0, 0);
            s[nt] = __builtin_amdgcn_mfma_f32_16x16x16bf16_1k(kp[nt][1], qp[mt][1], s[nt], 0, 0, 0);
        }

        int i = mt * 16 + l16;
        int icl = min(i, 48);
        int icode = (icl / 7) * 13 + (icl % 7) + 84;

        float val[4][4];
        float mx = -1e30f;
#pragma unroll
        for (int nt = 0; nt < 4; ++nt)
#pragma unroll
            for (int r = 0; r < 4; ++r) {
                int j = nt * 16 + quad * 4 + r;
                int idx = icode - ((jcp[nt] >> (8 * r)) & 255);
                idx = max(idx, 0);
                float vv = s[nt][r] + bias13[idx];
                vv = (j < 49) ? vv : -1e30f;
                val[nt][r] = vv;
                mx = fmaxf(mx, vv);
            }
        mx = fmaxf(mx, __shfl_xor(mx, 16));
        mx = fmaxf(mx, __shfl_xor(mx, 32));
        float sum = 0.f;
#pragma unroll
        for (int nt = 0; nt < 4; ++nt)
#pragma unroll
            for (int r = 0; r < 4; ++r) {
                float e = __expf(val[nt][r] - mx);
                val[nt][r] = e;
                sum += e;
            }
        sum += __shfl_xor(sum, 16);
        sum += __shfl_xor(sum, 32);
        float rs = 1.0f / sum;

        // P^T B-frags are just the packed vals: [k=j=kt*16+quad*4+r][col=i=l16]
        s16x4 pvs[4];
#pragma unroll
        for (int nt = 0; nt < 4; ++nt)
            pvs[nt] = pack4s(val[nt][0], val[nt][1], val[nt][2], val[nt][3]);

        // O^T = V^T * P^T : D[d=quad*4+r (within ntd half)][i=l16]
        f32x4 o0 = {}, o1 = {};
#pragma unroll
        for (int kt = 0; kt < 4; ++kt) {
            o0 = __builtin_amdgcn_mfma_f32_16x16x16bf16_1k(vp[kt][0], pvs[kt], o0, 0, 0, 0);
            o1 = __builtin_amdgcn_mfma_f32_16x16x16bf16_1k(vp[kt][1], pvs[kt], o1, 0, 0, 0);
        }

        if (i < 49) {
            *(s16x4*)(&xl[swz(i, h * 32 + quad * 4)]) =
                pack4s(o0[0] * rs, o0[1] * rs, o0[2] * rs, o0[3] * rs);
            *(s16x4*)(&xl[swz(i, h * 32 + 16 + quad * 4)]) =
                pack4s(o1[0] * rs, o1[1] * rs, o1[2] * rs, o1[3] * rs);
        }
    }

    __syncthreads();   // all heads' O written into sh_xo

    // ---- Phase 3: output projection; wave w covers out channels [h*32, h*32+32) ----
    f32x4 pacc[4][2] = {};
#pragma unroll
    for (int mt = 0; mt < 4; ++mt)
#pragma unroll
        for (int ks = 0; ks < 6; ++ks) {
            bf16x8 oa = *(const bf16x8*)(&xl[swz(rowc[mt], ks * 32 + quad * 8)]);
            pacc[mt][0] = __builtin_amdgcn_mfma_f32_16x16x32_bf16(oa, wf[0][ks], pacc[mt][0], 0, 0, 0);
            pacc[mt][1] = __builtin_amdgcn_mfma_f32_16x16x32_bf16(oa, wf[1][ks], pacc[mt][1], 0, 0, 0);
        }

    float pb0 = proj_b[h * 32 + l16];
    float pb1 = proj_b[h * 32 + 16 + l16];
#pragma unroll
    for (int mt = 0; mt < 4; ++mt)
#pragma unroll
        for (int r = 0; r < 4; ++r) {
            int i = mt * 16 + quad * 4 + r;
            if (alive && i < 49) {
                float* op = out + ((size_t)win * NTOK + i) * DIM + h * 32;
                op[l16]      = pacc[mt][0][r] + pb0;
                op[16 + l16] = pacc[mt][1][r] + pb1;
            }
        }
}

extern "C" void kernel_launch(void* const* d_in, const int* in_sizes, int n_in,
                              void* d_out, int out_size, void* d_ws, size_t ws_size,
                              hipStream_t stream) {
    const float* x      = (const float*)d_in[0];
    const float* D      = (const float*)d_in[1];
    const float* qkv_w  = (const float*)d_in[2];
    const float* qkv_b  = (const float*)d_in[3];
    const float* proj_w = (const float*)d_in[4];
    const float* proj_b = (const float*)d_in[5];
    const float* a_p    = (const float*)d_in[6];
    const float* b_p    = (const float*)d_in[7];
    const float* a_r    = (const float*)d_in[8];
    const float* b_r    = (const float*)d_in[9];
    float* out = (float*)d_out;

    const int B_ = in_sizes[0] / (NTOK * DIM);   // 2048 windows

    char* wsp = (char*)d_ws;
    bf16_t* wq = (bf16_t*)wsp; wsp += (size_t)QKV_DIM * DIM * 2;
    bf16_t* wp = (bf16_t*)wsp;

    cvt_weights<<<dim3((QKV_DIM * DIM + DIM * DIM + 255) / 256), dim3(256), 0, stream>>>(
        qkv_w, proj_w, wq, wp);

    fused_win_attn<<<dim3((B_ + 1) / 2), dim3(768), 0, stream>>>(
        x, D, wq, qkv_b, wp, proj_b, a_p, b_p, a_r, b_r, out, B_);
}